// Round 8
// baseline (178.546 us; speedup 1.0000x reference)
//
#include <hip/hip_runtime.h>

// Problem constants: x [B=16, C=256, H=128, W=128] f32 (NCHW)
#define BB 16
#define CC 256
#define HH 128
#define WW 128
#define HWSZ (HH * WW)          // 16384
#define HW4 (HWSZ / 4)          // 4096 float4 per plane
#define BHW (BB * HWSZ)         // 262144
#define TOTAL (BB * CC * HWSZ)  // 67108864

// Chunking: 4 chunks x 4 batches. Pool(chunk) reads 64 MiB of x into L3;
// gate(chunk) re-reads it (hopefully L3-hit) and NT-writes out.
#define NCHUNK 4
#define BPC (BB / NCHUNK)       // 4 batches per chunk

typedef float f32x4 __attribute__((ext_vector_type(4)));

// Kernel 1: channel pool (R6 structure, batch-sliced via b0).
// Block = 256 threads = 64 spatial float4 positions x 4 channel-chunks.
// Grid per chunk = BPC*HW4/64 = 256 blocks.
__global__ __launch_bounds__(256) void pool_kernel(const float* __restrict__ x,
                                                   float* __restrict__ pmax,
                                                   float* __restrict__ pmean,
                                                   int gpos0) {
    __shared__ float4 smax[256];
    __shared__ float4 ssum[256];
    int t     = threadIdx.x;
    int pos   = t & 63;
    int chunk = t >> 6;
    int gpos  = gpos0 + blockIdx.x * 64 + pos;   // global float4 index
    int b     = gpos >> 12;
    int hw4   = gpos & (HW4 - 1);
    const float4* xb = (const float4*)x + ((size_t)b << 20) + ((size_t)chunk << 18) + hw4;

    float4 v = xb[0];
    float mx0 = v.x, mx1 = v.y, mx2 = v.z, mx3 = v.w;
    float s0 = v.x, s1 = v.y, s2 = v.z, s3 = v.w;
    #pragma unroll 8
    for (int c = 1; c < 64; ++c) {
        float4 u = xb[(size_t)c << 12];
        mx0 = fmaxf(mx0, u.x); s0 += u.x;
        mx1 = fmaxf(mx1, u.y); s1 += u.y;
        mx2 = fmaxf(mx2, u.z); s2 += u.z;
        mx3 = fmaxf(mx3, u.w); s3 += u.w;
    }
    smax[t] = make_float4(mx0, mx1, mx2, mx3);
    ssum[t] = make_float4(s0, s1, s2, s3);
    __syncthreads();

    if (t < 64) {
        float4 m0 = smax[t],       m1 = smax[t + 64],
               m2 = smax[t + 128], m3 = smax[t + 192];
        float4 a0 = ssum[t],       a1 = ssum[t + 64],
               a2 = ssum[t + 128], a3 = ssum[t + 192];
        float4 m, a;
        m.x = fmaxf(fmaxf(m0.x, m1.x), fmaxf(m2.x, m3.x));
        m.y = fmaxf(fmaxf(m0.y, m1.y), fmaxf(m2.y, m3.y));
        m.z = fmaxf(fmaxf(m0.z, m1.z), fmaxf(m2.z, m3.z));
        m.w = fmaxf(fmaxf(m0.w, m1.w), fmaxf(m2.w, m3.w));
        const float inv = 1.0f / (float)CC;
        a.x = (a0.x + a1.x + a2.x + a3.x) * inv;
        a.y = (a0.y + a1.y + a2.y + a3.y) * inv;
        a.z = (a0.z + a1.z + a2.z + a3.z) * inv;
        a.w = (a0.w + a1.w + a2.w + a3.w) * inv;
        ((float4*)pmax)[gpos]  = m;
        ((float4*)pmean)[gpos] = a;
    }
}

// Kernel 2 (fused conv+BN+sigmoid+multiply, R6 structure, batch-sliced).
// Block = (b_local, rowgrp of 8 rows, csplit of 32 channels). Grid/chunk =
// BPC*16*8 = 512. Temporal x load (L3-hit expected), NT out store.
__global__ __launch_bounds__(256) void gate_kernel(const float* __restrict__ x,
                                                   const float* __restrict__ pmax,
                                                   const float* __restrict__ pmean,
                                                   const float* __restrict__ cw,
                                                   const float* __restrict__ cb,
                                                   const float* __restrict__ g,
                                                   const float* __restrict__ be,
                                                   const float* __restrict__ mu,
                                                   const float* __restrict__ var,
                                                   float* __restrict__ out,
                                                   int b0) {
    __shared__ float spm[14][134];
    __shared__ float spa[14][134];
    __shared__ float satt[8][128];
    __shared__ float wsm[98];
    __shared__ float sc[2];

    int t      = threadIdx.x;
    int bid    = blockIdx.x;
    int csplit = bid & 7;
    int rowgrp = (bid >> 3) & 15;
    int b      = b0 + (bid >> 7);
    int r0     = rowgrp << 3;

    if (t < 98) wsm[t] = cw[t];
    if (t == 0) {
        float scale = g[0] * rsqrtf(var[0] + 1e-5f);
        sc[0] = scale;
        sc[1] = cb[0] * scale + be[0] - mu[0] * scale;
    }

    // Phase A1: halo fill (rows r0-3 .. r0+10, cols -3..130, zero-padded)
    int pbase = b * HWSZ;
    #pragma unroll
    for (int r = 0; r < 14; ++r) {
        if (t < 134) {
            int gr = r0 + r - 3;
            int gc = t - 3;
            float vm = 0.0f, va = 0.0f;
            if ((unsigned)gr < (unsigned)HH && (unsigned)gc < (unsigned)WW) {
                int off = pbase + (gr << 7) + gc;
                vm = pmax[off];
                va = pmean[off];
            }
            spm[r][t] = vm;
            spa[r][t] = va;
        }
    }
    __syncthreads();

    // Phase A2: att tile (8 x 128), 4 positions per thread
    #pragma unroll
    for (int k = 0; k < 4; ++k) {
        int pos = t + (k << 8);
        int r   = pos >> 7;
        int c   = pos & 127;
        float acc = 0.0f;
        #pragma unroll
        for (int kh = 0; kh < 7; ++kh) {
            #pragma unroll
            for (int kw = 0; kw < 7; ++kw) {
                acc = fmaf(wsm[kh * 7 + kw],      spm[r + kh][c + kw], acc);
                acc = fmaf(wsm[49 + kh * 7 + kw], spa[r + kh][c + kw], acc);
            }
        }
        float y = fmaf(acc, sc[0], sc[1]);
        satt[r][c] = 1.0f / (1.0f + __expf(-y));
    }
    __syncthreads();

    // Phase B: stream 32 channels (4 KiB contiguous per plane per block)
    int row8 = t >> 5;            // 0..7
    int col4 = t & 31;            // 0..31 (float4 within row)
    int grow = r0 + row8;
    f32x4 a = *(const f32x4*)&satt[row8][col4 << 2];
    const f32x4* xv = (const f32x4*)x;
    f32x4*       ov = (f32x4*)out;
    int c0 = csplit << 5;
    int xi = (((b << 8) + c0) << 12) + (grow << 5) + col4;
    #pragma unroll 4
    for (int ch = 0; ch < 32; ++ch) {
        f32x4 v = xv[xi];
        v.x *= a.x; v.y *= a.y; v.z *= a.z; v.w *= a.w;
        __builtin_nontemporal_store(v, ov + xi);
        xi += HW4;                // next channel plane
    }
}

extern "C" void kernel_launch(void* const* d_in, const int* in_sizes, int n_in,
                              void* d_out, int out_size, void* d_ws, size_t ws_size,
                              hipStream_t stream) {
    const float* x   = (const float*)d_in[0];
    const float* cw  = (const float*)d_in[1];
    const float* cb  = (const float*)d_in[2];
    const float* g   = (const float*)d_in[3];
    const float* be  = (const float*)d_in[4];
    const float* mu  = (const float*)d_in[5];
    const float* var = (const float*)d_in[6];
    float* out = (float*)d_out;

    float* pmax  = (float*)d_ws;
    float* pmean = pmax + BHW;

    // 4 chunks of 4 batches: pool(c) fills L3 with x-chunk (64 MiB, 25% of
    // L3) -> gate(c) re-reads it. Kernel boundary provides the ordering.
    for (int c = 0; c < NCHUNK; ++c) {
        int gpos0 = c * BPC * HW4;            // first float4 index of chunk
        pool_kernel<<<BPC * HW4 / 64, 256, 0, stream>>>(x, pmax, pmean, gpos0);
        gate_kernel<<<BPC * 16 * 8, 256, 0, stream>>>(x, pmax, pmean, cw, cb,
                                                      g, be, mu, var, out,
                                                      c * BPC);
    }
}

// Round 9
// 137.324 us; speedup vs baseline: 1.3002x; 1.3002x over previous
//
#include <hip/hip_runtime.h>

// Problem constants: x [B=16, C=256, H=128, W=128] f32 (NCHW)
#define BB 16
#define CC 256
#define HH 128
#define WW 128
#define HWSZ (HH * WW)          // 16384
#define HW4 (HWSZ / 4)          // 4096 float4 per plane
#define BHW (BB * HWSZ)         // 262144
#define TOTAL (BB * CC * HWSZ)  // 67108864

typedef float f32x4 __attribute__((ext_vector_type(4)));

// Kernel 1: channel pool, C split 4-way within the block (R6/R4 structure —
// best measured). Block = 64 spatial float4 x 4 channel-chunks. Grid = 1024
// blocks -> 4 blocks/CU, 16 waves/CU.
__global__ __launch_bounds__(256) void pool_kernel(const float* __restrict__ x,
                                                   float* __restrict__ pmax,
                                                   float* __restrict__ pmean) {
    __shared__ float4 smax[256];
    __shared__ float4 ssum[256];
    int t     = threadIdx.x;
    int pos   = t & 63;
    int chunk = t >> 6;
    int gpos  = blockIdx.x * 64 + pos;
    int b     = gpos >> 12;
    int hw4   = gpos & (HW4 - 1);
    const float4* xb = (const float4*)x + ((size_t)b << 20) + ((size_t)chunk << 18) + hw4;

    float4 v = xb[0];
    float mx0 = v.x, mx1 = v.y, mx2 = v.z, mx3 = v.w;
    float s0 = v.x, s1 = v.y, s2 = v.z, s3 = v.w;
    #pragma unroll 8
    for (int c = 1; c < 64; ++c) {
        float4 u = xb[(size_t)c << 12];
        mx0 = fmaxf(mx0, u.x); s0 += u.x;
        mx1 = fmaxf(mx1, u.y); s1 += u.y;
        mx2 = fmaxf(mx2, u.z); s2 += u.z;
        mx3 = fmaxf(mx3, u.w); s3 += u.w;
    }
    smax[t] = make_float4(mx0, mx1, mx2, mx3);
    ssum[t] = make_float4(s0, s1, s2, s3);
    __syncthreads();

    if (t < 64) {
        float4 m0 = smax[t],       m1 = smax[t + 64],
               m2 = smax[t + 128], m3 = smax[t + 192];
        float4 a0 = ssum[t],       a1 = ssum[t + 64],
               a2 = ssum[t + 128], a3 = ssum[t + 192];
        float4 m, a;
        m.x = fmaxf(fmaxf(m0.x, m1.x), fmaxf(m2.x, m3.x));
        m.y = fmaxf(fmaxf(m0.y, m1.y), fmaxf(m2.y, m3.y));
        m.z = fmaxf(fmaxf(m0.z, m1.z), fmaxf(m2.z, m3.z));
        m.w = fmaxf(fmaxf(m0.w, m1.w), fmaxf(m2.w, m3.w));
        const float inv = 1.0f / (float)CC;
        a.x = (a0.x + a1.x + a2.x + a3.x) * inv;
        a.y = (a0.y + a1.y + a2.y + a3.y) * inv;
        a.z = (a0.z + a1.z + a2.z + a3.z) * inv;
        a.w = (a0.w + a1.w + a2.w + a3.w) * inv;
        ((float4*)pmax)[gpos]  = m;
        ((float4*)pmean)[gpos] = a;
    }
}

// Kernel 2 (fused conv+BN+sigmoid+multiply, R6 structure — best measured).
// Block = (b, rowgrp of 8 rows, csplit of 32 channels). Grid = 2048,
// ~8 blocks/CU. Phase A: LDS halo + 8x128 att tile (redundant across csplit,
// free under the memory stream). Phase B: stream 32 channels, temporal x
// load, NT out store.
__global__ __launch_bounds__(256) void gate_kernel(const float* __restrict__ x,
                                                   const float* __restrict__ pmax,
                                                   const float* __restrict__ pmean,
                                                   const float* __restrict__ cw,
                                                   const float* __restrict__ cb,
                                                   const float* __restrict__ g,
                                                   const float* __restrict__ be,
                                                   const float* __restrict__ mu,
                                                   const float* __restrict__ var,
                                                   float* __restrict__ out) {
    __shared__ float spm[14][134];
    __shared__ float spa[14][134];
    __shared__ float satt[8][128];
    __shared__ float wsm[98];
    __shared__ float sc[2];

    int t      = threadIdx.x;
    int bid    = blockIdx.x;
    int csplit = bid & 7;
    int rowgrp = (bid >> 3) & 15;
    int b      = bid >> 7;
    int r0     = rowgrp << 3;

    if (t < 98) wsm[t] = cw[t];
    if (t == 0) {
        float scale = g[0] * rsqrtf(var[0] + 1e-5f);
        sc[0] = scale;
        sc[1] = cb[0] * scale + be[0] - mu[0] * scale;
    }

    // Phase A1: halo fill (rows r0-3 .. r0+10, cols -3..130, zero-padded)
    int pbase = b * HWSZ;
    #pragma unroll
    for (int r = 0; r < 14; ++r) {
        if (t < 134) {
            int gr = r0 + r - 3;
            int gc = t - 3;
            float vm = 0.0f, va = 0.0f;
            if ((unsigned)gr < (unsigned)HH && (unsigned)gc < (unsigned)WW) {
                int off = pbase + (gr << 7) + gc;
                vm = pmax[off];
                va = pmean[off];
            }
            spm[r][t] = vm;
            spa[r][t] = va;
        }
    }
    __syncthreads();

    // Phase A2: att tile (8 x 128), 4 positions per thread
    #pragma unroll
    for (int k = 0; k < 4; ++k) {
        int pos = t + (k << 8);
        int r   = pos >> 7;
        int c   = pos & 127;
        float acc = 0.0f;
        #pragma unroll
        for (int kh = 0; kh < 7; ++kh) {
            #pragma unroll
            for (int kw = 0; kw < 7; ++kw) {
                acc = fmaf(wsm[kh * 7 + kw],      spm[r + kh][c + kw], acc);
                acc = fmaf(wsm[49 + kh * 7 + kw], spa[r + kh][c + kw], acc);
            }
        }
        float y = fmaf(acc, sc[0], sc[1]);
        satt[r][c] = 1.0f / (1.0f + __expf(-y));
    }
    __syncthreads();

    // Phase B: stream 32 channels (4 KiB contiguous per plane per block)
    int row8 = t >> 5;            // 0..7
    int col4 = t & 31;            // 0..31 (float4 within row)
    int grow = r0 + row8;
    f32x4 a = *(const f32x4*)&satt[row8][col4 << 2];
    const f32x4* xv = (const f32x4*)x;
    f32x4*       ov = (f32x4*)out;
    int c0 = csplit << 5;
    int xi = (((b << 8) + c0) << 12) + (grow << 5) + col4;
    #pragma unroll 4
    for (int ch = 0; ch < 32; ++ch) {
        f32x4 v = xv[xi];
        v.x *= a.x; v.y *= a.y; v.z *= a.z; v.w *= a.w;
        __builtin_nontemporal_store(v, ov + xi);
        xi += HW4;                // next channel plane
    }
}

extern "C" void kernel_launch(void* const* d_in, const int* in_sizes, int n_in,
                              void* d_out, int out_size, void* d_ws, size_t ws_size,
                              hipStream_t stream) {
    const float* x   = (const float*)d_in[0];
    const float* cw  = (const float*)d_in[1];
    const float* cb  = (const float*)d_in[2];
    const float* g   = (const float*)d_in[3];
    const float* be  = (const float*)d_in[4];
    const float* mu  = (const float*)d_in[5];
    const float* var = (const float*)d_in[6];
    float* out = (float*)d_out;

    float* pmax  = (float*)d_ws;
    float* pmean = pmax + BHW;

    pool_kernel<<<BHW / 4 / 64, 256, 0, stream>>>(x, pmax, pmean);
    gate_kernel<<<BB * 16 * 8, 256, 0, stream>>>(x, pmax, pmean, cw, cb, g, be, mu, var, out);
}